// Round 13
// baseline (48.266 us; speedup 1.0000x reference)
//
#include <hip/hip_runtime.h>
#include <hip/hip_bf16.h>
#include <stdint.h>

#define DEVI __device__ __forceinline__

typedef __attribute__((ext_vector_type(8))) short short8;
typedef __attribute__((ext_vector_type(16))) float f32x16;
typedef __attribute__((ext_vector_type(4))) float f32x4;
typedef __attribute__((ext_vector_type(2))) unsigned int uint2v;
typedef unsigned short ushortT;

union U8 { short8 s8; unsigned u[4]; };

DEVI unsigned short f2bf(float f) {
  unsigned u = __builtin_bit_cast(unsigned, f);
  u += 0x7fffu + ((u >> 16) & 1u);
  return (unsigned short)(u >> 16);
}
DEVI unsigned pk2(float lo, float hi) {
  return (unsigned)f2bf(lo) | ((unsigned)f2bf(hi) << 16);
}
DEVI unsigned cvtpk(float lo, float hi) {
  unsigned r;
  asm("v_cvt_pk_bf16_f32 %0, %1, %2" : "=v"(r) : "v"(lo), "v"(hi));
  return r;
}
DEVI float exp2a(float x) { return __builtin_amdgcn_exp2f(x); }

#define MFMA32 __builtin_amdgcn_mfma_f32_32x32x16_bf16
// Q pre-scaled by C = 0.125*log2(e): p = exp(S/8) = exp2(S'). Logits statically
// bounded for this problem (p <= ~e^6): no running max needed, and s-chunk
// partials (O, l) combine by simple addition.
#define C_L2E 0.18033688011112042f

// ============ aux kernel: prep (blocks 0..255) + gram (blocks 256..383) ========
// prep: fragment-pack st K and V (bf16), R9 32x32 format.
// kfp[bh][t][f=half*4+kk][lane][8]: elem j = K[c=kk*16+hi*8+j][s=t*64+half*32+ln]
// vfp: PERMUTED pack so PV B-operand equals the lane's own cvtpk(P) outputs.
// gram: Mws[gb] = 0.125 * partial(V_img K_img^T) over 512 s (gb = bh*8+chunk).
__global__ __launch_bounds__(256) void aux_kernel(
    const float* __restrict__ img, const float* __restrict__ st,
    ushortT* __restrict__ kfp, ushortT* __restrict__ vfp,
    float* __restrict__ Mws) {
  __shared__ __align__(16) char pool[32768];
  const int tid = threadIdx.x;
  const int bid = blockIdx.x;
  const int w = tid >> 6, lane = tid & 63, hi = lane >> 5, ln = lane & 31;

  if (bid < 256) {
    // ----------------------------- prep role ------------------------------
    const int bh = bid >> 4, t = bid & 15;
    const int b = bh >> 3, h = bh & 7;
    const float* kbase = st + ((size_t)(b * 1536 + 512 + h * 64)) * 1024;
    const float* vbase = st + ((size_t)(b * 1536 + 1024 + h * 64)) * 1024;
    ushortT* ko = kfp + ((size_t)bh * 16 + t) * 4096;
    ushortT* vo = vfp + ((size_t)bh * 16 + t) * 4096;

    float (*kf)[65] = (float (*)[65])pool;  // [64][65]
    {
      const int c = tid >> 2, s16 = (tid & 3) * 16;
      const float* kp = kbase + (size_t)c * 1024 + t * 64 + s16;
      f32x4 a = *(const f32x4*)kp, b4 = *(const f32x4*)(kp + 4),
            c4 = *(const f32x4*)(kp + 8), d4 = *(const f32x4*)(kp + 12);
#pragma unroll
      for (int j = 0; j < 4; ++j) {
        kf[c][s16 + j] = a[j];
        kf[c][s16 + 4 + j] = b4[j];
        kf[c][s16 + 8 + j] = c4[j];
        kf[c][s16 + 12 + j] = d4[j];
      }
    }
    // V: permuted fragment pack (i<4 -> lane-half 0, i>=4 -> lane-half 1)
#pragma unroll
    for (int rep = 0; rep < 2; ++rep) {
      const int pair = tid + rep * 256;
      const int c = pair >> 3, oct = pair & 7;
      const float* vp = vbase + (size_t)c * 1024 + t * 64 + oct * 8;
      f32x4 lo = *(const f32x4*)vp, hp = *(const f32x4*)(vp + 4);
      uint2v la, ha;
      la[0] = pk2(lo[0], lo[1]); la[1] = pk2(lo[2], lo[3]);
      ha[0] = pk2(hp[0], hp[1]); ha[1] = pk2(hp[2], hp[3]);
      const int ci = c >> 5, lnn = c & 31;
      const int ss = oct >> 2, kk2 = (oct >> 1) & 1, o1 = oct & 1;
      const int f = ss * 4 + kk2 * 2 + ci;
      *(uint2v*)(vo + ((size_t)f * 64 + lnn) * 8 + o1 * 4) = la;
      *(uint2v*)(vo + ((size_t)f * 64 + 32 + lnn) * 8 + o1 * 4) = ha;
    }
    __syncthreads();
    {
      const int kk = w;
#pragma unroll
      for (int half = 0; half < 2; ++half) {
        float v8[8];
#pragma unroll
        for (int j = 0; j < 8; ++j) v8[j] = kf[kk * 16 + hi * 8 + j][half * 32 + ln];
        U8 u;
#pragma unroll
        for (int i = 0; i < 4; ++i) u.u[i] = pk2(v8[2 * i], v8[2 * i + 1]);
        *(short8*)(ko + ((size_t)(half * 4 + kk) * 64 + lane) * 8) = u.s8;
      }
    }
  } else {
    // ----------------------------- gram role ------------------------------
    const int gb = bid - 256;  // 0..127 = 16 bh * 8 chunks(512 s)
    const int bh = gb >> 3, chunk = gb & 7;
    const int b = bh >> 3, h = bh & 7;
    const float* kbase = img + ((size_t)(b * 1536 + 512 + h * 64)) * 4096;
    const float* vbase = img + ((size_t)(b * 1536 + 1024 + h * 64)) * 4096;

    f32x16 m00 = {}, m01 = {}, m10 = {}, m11 = {};
    const int sbeg = chunk * 512 + w * 128;
    for (int s0 = sbeg; s0 < sbeg + 128; s0 += 16) {
      const int sa = s0 + hi * 8;
      short8 av[2], bk[2];
#pragma unroll
      for (int ci = 0; ci < 2; ++ci) {
        const float* vp = vbase + (size_t)(ci * 32 + ln) * 4096 + sa;
        f32x4 lo = *(const f32x4*)vp, hp = *(const f32x4*)(vp + 4);
        U8 u;
        u.u[0] = pk2(lo[0], lo[1]); u.u[1] = pk2(lo[2], lo[3]);
        u.u[2] = pk2(hp[0], hp[1]); u.u[3] = pk2(hp[2], hp[3]);
        av[ci] = u.s8;
      }
#pragma unroll
      for (int cj = 0; cj < 2; ++cj) {
        const float* kp = kbase + (size_t)(cj * 32 + ln) * 4096 + sa;
        f32x4 lo = *(const f32x4*)kp, hp = *(const f32x4*)(kp + 4);
        U8 u;
        u.u[0] = pk2(lo[0], lo[1]); u.u[1] = pk2(lo[2], lo[3]);
        u.u[2] = pk2(hp[0], hp[1]); u.u[3] = pk2(hp[2], hp[3]);
        bk[cj] = u.s8;
      }
      m00 = MFMA32(av[0], bk[0], m00, 0, 0, 0);
      m01 = MFMA32(av[0], bk[1], m01, 0, 0, 0);
      m10 = MFMA32(av[1], bk[0], m10, 0, 0, 0);
      m11 = MFMA32(av[1], bk[1], m11, 0, 0, 0);
    }

    float (*part)[64][64] = (float (*)[64][64])pool;  // [2][64][64]
    if (w < 2) {
#pragma unroll
      for (int q = 0; q < 16; ++q) {
        const int cr = (q & 3) + 8 * (q >> 2) + 4 * hi;
        part[w][cr][ln] = m00[q];
        part[w][cr][32 + ln] = m01[q];
        part[w][32 + cr][ln] = m10[q];
        part[w][32 + cr][32 + ln] = m11[q];
      }
    }
    __syncthreads();
    if (w >= 2) {
      const int pw = w - 2;
#pragma unroll
      for (int q = 0; q < 16; ++q) {
        const int cr = (q & 3) + 8 * (q >> 2) + 4 * hi;
        part[pw][cr][ln] += m00[q];
        part[pw][cr][32 + ln] += m01[q];
        part[pw][32 + cr][ln] += m10[q];
        part[pw][32 + cr][32 + ln] += m11[q];
      }
    }
    __syncthreads();
#pragma unroll
    for (int i = 0; i < 16; ++i) {
      const int e = tid + i * 256;
      const int c = e >> 6, cp = e & 63;
      Mws[(size_t)gb * 4096 + c * 64 + cp] =
          (part[0][c][cp] + part[1][c][cp]) * 0.125f;
    }
  }
}

// ============ main kernel: attn (blocks 0..1023) + st2 (1024..1087) ============
// attn: block = 64 t = 2 t-groups x 2 s-chunks(512 s). Each wave runs a fully
// PRIVATE pipeline: its own 2 x 8 KB LDS double-buffer, 16 sub-tiles of 32 s,
// per-wave counted vmcnt sync — ZERO barriers in the main loop. s-chunk
// partials (no-max softmax) merge by addition at the end (2 barriers total).
DEVI void stage_sub(ushortT* mybuf, int buf, const ushortT* kt, const ushortT* vt,
                    int half, int lane) {
  ushortT* dst = mybuf + buf * 4096;  // [8 slots][512]
#pragma unroll
  for (int j = 0; j < 4; ++j) {
    const ushortT* src = kt + (size_t)(half * 4 + j) * 512 + lane * 8;
    __builtin_amdgcn_global_load_lds(
        (const __attribute__((address_space(1))) void*)src,
        (__attribute__((address_space(3))) void*)(dst + j * 512), 16, 0, 0);
  }
#pragma unroll
  for (int j = 0; j < 4; ++j) {
    const ushortT* src = vt + (size_t)(half * 4 + j) * 512 + lane * 8;
    __builtin_amdgcn_global_load_lds(
        (const __attribute__((address_space(1))) void*)src,
        (__attribute__((address_space(3))) void*)(dst + (4 + j) * 512), 16, 0, 0);
  }
}

DEVI void st2_body(const float* __restrict__ st, const float* __restrict__ Mws,
                   float* __restrict__ out1, int sb, int tid, char* pool) {
  const int bh = sb >> 2, tt = sb & 3;
  const int b = bh >> 3, h = bh & 7;
  const float* qbase = st + ((size_t)(b * 1536 + h * 64)) * 1024;
  float* o1 = out1 + ((size_t)(b * 512 + h * 64)) * 1024;
  char* msb = pool;  // 16 KB: Ms[64][64] XOR-swizzled rows

#pragma unroll
  for (int i = 0; i < 16; ++i) {
    const int e = tid + i * 256;
    const int c = e >> 6, cp = e & 63;
    const float* mp = Mws + (size_t)bh * 8 * 4096 + c * 64 + cp;
    float s = 0.f;
#pragma unroll
    for (int ch = 0; ch < 8; ++ch) s += mp[(size_t)ch * 4096];
    *(float*)(msb + c * 256 + ((cp * 4) ^ ((c & 7) << 5))) = s;
  }
  __syncthreads();

  const int w = tid >> 6, lane = tid & 63, hi = lane >> 5, ln = lane & 31;

  short8 aM0[4], aM1[4];
#pragma unroll
  for (int k = 0; k < 4; ++k) {
#pragma unroll
    for (int ci = 0; ci < 2; ++ci) {
      const int row = ci * 32 + ln;
      const int bo = k * 64 + hi * 32;
      const char* rp = msb + row * 256;
      const int swz = (row & 7) << 5;
      f32x4 lo = *(const f32x4*)(rp + (bo ^ swz));
      f32x4 hp = *(const f32x4*)(rp + ((bo + 16) ^ swz));
      U8 u;
      u.u[0] = pk2(lo[0], lo[1]); u.u[1] = pk2(lo[2], lo[3]);
      u.u[2] = pk2(hp[0], hp[1]); u.u[3] = pk2(hp[2], hp[3]);
      if (ci) aM1[k] = u.s8; else aM0[k] = u.s8;
    }
  }

#pragma unroll
  for (int nt = 0; nt < 2; ++nt) {
    const int t = tt * 256 + w * 64 + nt * 32 + ln;
    short8 bq[4];
#pragma unroll
    for (int k = 0; k < 4; ++k) {
      const float* qp = qbase + (size_t)(k * 16 + hi * 8) * 1024 + t;
      float q8[8];
#pragma unroll
      for (int j = 0; j < 8; ++j) q8[j] = qp[(size_t)j * 1024];
      U8 u;
#pragma unroll
      for (int i = 0; i < 4; ++i) u.u[i] = pk2(q8[2 * i], q8[2 * i + 1]);
      bq[k] = u.s8;
    }
    f32x16 a0 = {}, a1 = {};
#pragma unroll
    for (int k = 0; k < 4; ++k) {
      a0 = MFMA32(aM0[k], bq[k], a0, 0, 0, 0);
      a1 = MFMA32(aM1[k], bq[k], a1, 0, 0, 0);
    }
#pragma unroll
    for (int q = 0; q < 16; ++q) {
      const int cr = (q & 3) + 8 * (q >> 2) + 4 * hi;
      o1[(size_t)cr * 1024 + t] = a0[q];
      o1[(size_t)(cr + 32) * 1024 + t] = a1[q];
    }
  }
}

template <bool WITH_ST2>
__global__ __launch_bounds__(256, 2) void main_kernel(
    const float* __restrict__ img, const ushortT* __restrict__ kfp,
    const ushortT* __restrict__ vfp, const float* __restrict__ st,
    const float* __restrict__ Mws, float* __restrict__ out0,
    float* __restrict__ out1) {
  __shared__ __align__(16) char pool[65536];  // 4 waves x [2][8][512] ushorts
  const int tid = threadIdx.x;
  const int bid = blockIdx.x;

  if (WITH_ST2 && bid >= 1024) {
    st2_body(st, Mws, out1, bid - 1024, tid, pool);
    return;
  }

  const int w = tid >> 6, lane = tid & 63, hi = lane >> 5, ln = lane & 31;
  const int tg = w & 1, sch = w >> 1;  // t-group, s-chunk
  const int bh = bid >> 6, tb = bid & 63;
  const int b = bh >> 3, h = bh & 7;
  const float* qbase = img + ((size_t)(b * 1536 + h * 64)) * 4096;
  float* obase = out0 + ((size_t)(b * 512 + h * 64)) * 4096;
  const int tcol = tb * 64 + tg * 32 + ln;

  ushortT* mybuf = (ushortT*)(pool + w * 16384);
  // wave's s-range: sch*512 .. +512 = global sub-tiles g = sch*16 + st
  const ushortT* kbh = kfp + (size_t)bh * 16 * 4096;
  const ushortT* vbh = vfp + (size_t)bh * 16 * 4096;

  // Q fragments, pre-scaled by C_L2E: elem j = C*Q[k*16+hi*8+j][tcol].
  // Issued and consumed before staging so the loop's vmcnt counts stages only.
  short8 qf[4];
#pragma unroll
  for (int k = 0; k < 4; ++k) {
    const float* qp = qbase + (size_t)(k * 16 + hi * 8) * 4096 + tcol;
    float q8[8];
#pragma unroll
    for (int j = 0; j < 8; ++j) q8[j] = qp[(size_t)j * 4096] * C_L2E;
    U8 u;
#pragma unroll
    for (int i = 0; i < 4; ++i) u.u[i] = pk2(q8[2 * i], q8[2 * i + 1]);
    qf[k] = u.s8;
  }

  // prologue: stage sub-tiles 0 and 1 into the private double-buffer
  {
    const int g0 = sch * 16, g1 = g0 + 1;
    stage_sub(mybuf, 0, kbh + (size_t)(g0 >> 1) * 4096, vbh + (size_t)(g0 >> 1) * 4096,
              g0 & 1, lane);
    stage_sub(mybuf, 1, kbh + (size_t)(g1 >> 1) * 4096, vbh + (size_t)(g1 >> 1) * 4096,
              g1 & 1, lane);
  }

  f32x16 o0 = {}, o1 = {};
  float la0 = 0.f, la1 = 0.f, la2 = 0.f, la3 = 0.f;

#pragma unroll
  for (int i = 0; i < 16; ++i) {
    // per-wave counted sync: stage(i) must be retired; stage(i+1) stays in
    // flight (8 newest ops). Last iteration drains everything.
    if (i < 15)
      asm volatile("s_waitcnt vmcnt(8)" ::: "memory");
    else
      asm volatile("s_waitcnt vmcnt(0)" ::: "memory");

    const ushortT* B = mybuf + (i & 1) * 4096;

    // QK^T over this 32-s sub-tile: D[s][t], 4 MFMA chain
    f32x16 sc = {};
    {
      short8 k0 = *(const short8*)(B + 0 * 512 + lane * 8);
      short8 k1 = *(const short8*)(B + 1 * 512 + lane * 8);
      short8 k2 = *(const short8*)(B + 2 * 512 + lane * 8);
      short8 k3 = *(const short8*)(B + 3 * 512 + lane * 8);
      sc = MFMA32(k0, qf[0], sc, 0, 0, 0);
      sc = MFMA32(k1, qf[1], sc, 0, 0, 0);
      sc = MFMA32(k2, qf[2], sc, 0, 0, 0);
      sc = MFMA32(k3, qf[3], sc, 0, 0, 0);
    }

    // p = exp2(S'); l accumulated (no max, no rescale)
#pragma unroll
    for (int q = 0; q < 16; q += 4) {
      float p0 = exp2a(sc[q]);
      float p1 = exp2a(sc[q + 1]);
      float p2 = exp2a(sc[q + 2]);
      float p3 = exp2a(sc[q + 3]);
      sc[q] = p0; sc[q + 1] = p1; sc[q + 2] = p2; sc[q + 3] = p3;
      la0 += p0; la1 += p1; la2 += p2; la3 += p3;
    }

    // PV: B-frags are the lane's own cvtpk outputs (permuted V pack)
    {
      U8 B0, B1;
      B0.u[0] = cvtpk(sc[0], sc[1]);   B0.u[1] = cvtpk(sc[2], sc[3]);
      B0.u[2] = cvtpk(sc[4], sc[5]);   B0.u[3] = cvtpk(sc[6], sc[7]);
      B1.u[0] = cvtpk(sc[8], sc[9]);   B1.u[1] = cvtpk(sc[10], sc[11]);
      B1.u[2] = cvtpk(sc[12], sc[13]); B1.u[3] = cvtpk(sc[14], sc[15]);
      short8 v0 = *(const short8*)(B + 4 * 512 + lane * 8);
      short8 v1 = *(const short8*)(B + 5 * 512 + lane * 8);
      short8 v2 = *(const short8*)(B + 6 * 512 + lane * 8);
      short8 v3 = *(const short8*)(B + 7 * 512 + lane * 8);
      o0 = MFMA32(v0, B0.s8, o0, 0, 0, 0);
      o1 = MFMA32(v1, B0.s8, o1, 0, 0, 0);
      o0 = MFMA32(v2, B1.s8, o0, 0, 0, 0);
      o1 = MFMA32(v3, B1.s8, o1, 0, 0, 0);
    }

    // stage sub-tile i+2 into buffer (i&1): its ds_reads are consumed (the
    // compiler's lgkmcnt waits before the MFMAs above guarantee retirement)
    if (i + 2 < 16) {
      const int g = sch * 16 + i + 2;
      stage_sub(mybuf, i & 1, kbh + (size_t)(g >> 1) * 4096,
                vbh + (size_t)(g >> 1) * 4096, g & 1, lane);
    }
  }

  float l = (la0 + la1) + (la2 + la3);
  l += __shfl_xor(l, 32);

  // merge the two s-chunks (sch 0 <- 1) by addition; normalize + store
  __syncthreads();
  float (*mrg)[64][33] = (float (*)[64][33])pool;
  if (sch == 1) {
#pragma unroll
    for (int q = 0; q < 16; ++q) {
      mrg[tg][lane][q] = o0[q];
      mrg[tg][lane][16 + q] = o1[q];
    }
    mrg[tg][lane][32] = l;
  }
  __syncthreads();
  if (sch == 0) {
    const float linv = 1.0f / (l + mrg[tg][lane][32]);
#pragma unroll
    for (int q = 0; q < 16; ++q) {
      const int c = (q & 3) + 8 * (q >> 2) + 4 * hi;
      obase[(size_t)c * 4096 + tcol] = (o0[q] + mrg[tg][lane][q]) * linv;
      obase[(size_t)(c + 32) * 4096 + tcol] = (o1[q] + mrg[tg][lane][16 + q]) * linv;
    }
  }
}

// standalone st2 for the small-ws fallback (runs after main; out1 reuse safe)
__global__ __launch_bounds__(256) void st2_kernel(
    const float* __restrict__ st, const float* __restrict__ Mws,
    float* __restrict__ out1) {
  __shared__ __align__(16) char pool[16384];
  st2_body(st, Mws, out1, blockIdx.x, threadIdx.x, pool);
}

extern "C" void kernel_launch(void* const* d_in, const int* in_sizes, int n_in,
                              void* d_out, int out_size, void* d_ws, size_t ws_size,
                              hipStream_t stream) {
  const float* img = (const float*)d_in[0];
  const float* st = (const float*)d_in[1];
  float* out0 = (float*)d_out;
  float* out1 = out0 + (size_t)2 * 512 * 4096;
  char* ws = (char*)d_ws;
  const size_t MB = 1u << 20;

  ushortT* kfp;
  ushortT* vfp;
  float* Ms;
  bool fits = ws_size >= 6 * MB;
  if (fits) {
    kfp = (ushortT*)ws; vfp = (ushortT*)(ws + 2 * MB); Ms = (float*)(ws + 4 * MB);
  } else {
    // stash packed K/V in out1's region (4 MB); st2 runs after main and
    // overwrites it last (kernel order on the stream guarantees safety)
    kfp = (ushortT*)out1; vfp = (ushortT*)((char*)out1 + 2 * MB);
    Ms = (float*)ws;  // needs 2 MB
  }

  hipLaunchKernelGGL(aux_kernel, dim3(384), dim3(256), 0, stream, img, st, kfp,
                     vfp, Ms);
  if (fits) {
    hipLaunchKernelGGL((main_kernel<true>), dim3(1088), dim3(256), 0, stream, img,
                       kfp, vfp, st, Ms, out0, out1);
  } else {
    hipLaunchKernelGGL((main_kernel<false>), dim3(1024), dim3(256), 0, stream, img,
                       kfp, vfp, st, Ms, out0, out1);
    hipLaunchKernelGGL(st2_kernel, dim3(64), dim3(256), 0, stream, st, Ms, out1);
  }
}

// Round 14
// 43.667 us; speedup vs baseline: 1.1053x; 1.1053x over previous
//
#include <hip/hip_runtime.h>
#include <hip/hip_bf16.h>
#include <stdint.h>

#define DEVI __device__ __forceinline__

typedef __attribute__((ext_vector_type(8))) short short8;
typedef __attribute__((ext_vector_type(16))) float f32x16;
typedef __attribute__((ext_vector_type(4))) float f32x4;
typedef __attribute__((ext_vector_type(2))) unsigned int uint2v;
typedef unsigned short ushortT;

union U8 { short8 s8; unsigned u[4]; };

DEVI unsigned cvtpk(float lo, float hi) {
  unsigned r;
  asm("v_cvt_pk_bf16_f32 %0, %1, %2" : "=v"(r) : "v"(lo), "v"(hi));
  return r;
}
DEVI float exp2a(float x) { return __builtin_amdgcn_exp2f(x); }

#define MFMA32 __builtin_amdgcn_mfma_f32_32x32x16_bf16
// Q pre-scaled by C = 0.125*log2(e): p = exp(S/8) = exp2(S'). Logits statically
// bounded for this problem (p <= ~e^6): no running max needed; s-chunk
// partials (O, l) combine by simple addition.
#define C_L2E 0.18033688011112042f

// ============ aux kernel: prep (blocks 0..255) + gram (blocks 256..383) ========
// prep: fragment-pack st K and V (bf16), 32x32 format.
// kfp[bh][t][f=half*4+kk][lane][8]: elem j = K[c=kk*16+hi*8+j][s=t*64+half*32+ln]
// vfp: PERMUTED pack so PV B-operand equals the lane's own cvtpk(P) outputs.
// gram: Mws[gb] = 0.125 * partial(V_img K_img^T) over 512 s (gb = bh*8+chunk).
__global__ __launch_bounds__(256) void aux_kernel(
    const float* __restrict__ img, const float* __restrict__ st,
    ushortT* __restrict__ kfp, ushortT* __restrict__ vfp,
    float* __restrict__ Mws) {
  __shared__ __align__(16) char pool[32768];
  const int tid = threadIdx.x;
  const int bid = blockIdx.x;
  const int w = tid >> 6, lane = tid & 63, hi = lane >> 5, ln = lane & 31;

  if (bid < 256) {
    // ----------------------------- prep role ------------------------------
    const int bh = bid >> 4, t = bid & 15;
    const int b = bh >> 3, h = bh & 7;
    const float* kbase = st + ((size_t)(b * 1536 + 512 + h * 64)) * 1024;
    const float* vbase = st + ((size_t)(b * 1536 + 1024 + h * 64)) * 1024;
    ushortT* ko = kfp + ((size_t)bh * 16 + t) * 4096;
    ushortT* vo = vfp + ((size_t)bh * 16 + t) * 4096;

    float (*kf)[65] = (float (*)[65])pool;  // [64][65]
    {
      const int c = tid >> 2, s16 = (tid & 3) * 16;
      const float* kp = kbase + (size_t)c * 1024 + t * 64 + s16;
      f32x4 a = *(const f32x4*)kp, b4 = *(const f32x4*)(kp + 4),
            c4 = *(const f32x4*)(kp + 8), d4 = *(const f32x4*)(kp + 12);
#pragma unroll
      for (int j = 0; j < 4; ++j) {
        kf[c][s16 + j] = a[j];
        kf[c][s16 + 4 + j] = b4[j];
        kf[c][s16 + 8 + j] = c4[j];
        kf[c][s16 + 12 + j] = d4[j];
      }
    }
    // V: permuted fragment pack (i<4 -> lane-half 0, i>=4 -> lane-half 1)
#pragma unroll
    for (int rep = 0; rep < 2; ++rep) {
      const int pair = tid + rep * 256;
      const int c = pair >> 3, oct = pair & 7;
      const float* vp = vbase + (size_t)c * 1024 + t * 64 + oct * 8;
      f32x4 lo = *(const f32x4*)vp, hp = *(const f32x4*)(vp + 4);
      uint2v la, ha;
      la[0] = cvtpk(lo[0], lo[1]); la[1] = cvtpk(lo[2], lo[3]);
      ha[0] = cvtpk(hp[0], hp[1]); ha[1] = cvtpk(hp[2], hp[3]);
      const int ci = c >> 5, lnn = c & 31;
      const int ss = oct >> 2, kk2 = (oct >> 1) & 1, o1 = oct & 1;
      const int f = ss * 4 + kk2 * 2 + ci;
      *(uint2v*)(vo + ((size_t)f * 64 + lnn) * 8 + o1 * 4) = la;
      *(uint2v*)(vo + ((size_t)f * 64 + 32 + lnn) * 8 + o1 * 4) = ha;
    }
    __syncthreads();
    {
      const int kk = w;
#pragma unroll
      for (int half = 0; half < 2; ++half) {
        float v8[8];
#pragma unroll
        for (int j = 0; j < 8; ++j) v8[j] = kf[kk * 16 + hi * 8 + j][half * 32 + ln];
        U8 u;
#pragma unroll
        for (int i = 0; i < 4; ++i) u.u[i] = cvtpk(v8[2 * i], v8[2 * i + 1]);
        *(short8*)(ko + ((size_t)(half * 4 + kk) * 64 + lane) * 8) = u.s8;
      }
    }
  } else {
    // ----------------------------- gram role ------------------------------
    const int gb = bid - 256;  // 0..127 = 16 bh * 8 chunks(512 s)
    const int bh = gb >> 3, chunk = gb & 7;
    const int b = bh >> 3, h = bh & 7;
    const float* kbase = img + ((size_t)(b * 1536 + 512 + h * 64)) * 4096;
    const float* vbase = img + ((size_t)(b * 1536 + 1024 + h * 64)) * 4096;

    f32x16 m00 = {}, m01 = {}, m10 = {}, m11 = {};
    const int sbeg = chunk * 512 + w * 128;
    for (int s0 = sbeg; s0 < sbeg + 128; s0 += 16) {
      const int sa = s0 + hi * 8;
      short8 av[2], bk[2];
#pragma unroll
      for (int ci = 0; ci < 2; ++ci) {
        const float* vp = vbase + (size_t)(ci * 32 + ln) * 4096 + sa;
        f32x4 lo = *(const f32x4*)vp, hp = *(const f32x4*)(vp + 4);
        U8 u;
        u.u[0] = cvtpk(lo[0], lo[1]); u.u[1] = cvtpk(lo[2], lo[3]);
        u.u[2] = cvtpk(hp[0], hp[1]); u.u[3] = cvtpk(hp[2], hp[3]);
        av[ci] = u.s8;
      }
#pragma unroll
      for (int cj = 0; cj < 2; ++cj) {
        const float* kp = kbase + (size_t)(cj * 32 + ln) * 4096 + sa;
        f32x4 lo = *(const f32x4*)kp, hp = *(const f32x4*)(kp + 4);
        U8 u;
        u.u[0] = cvtpk(lo[0], lo[1]); u.u[1] = cvtpk(lo[2], lo[3]);
        u.u[2] = cvtpk(hp[0], hp[1]); u.u[3] = cvtpk(hp[2], hp[3]);
        bk[cj] = u.s8;
      }
      m00 = MFMA32(av[0], bk[0], m00, 0, 0, 0);
      m01 = MFMA32(av[0], bk[1], m01, 0, 0, 0);
      m10 = MFMA32(av[1], bk[0], m10, 0, 0, 0);
      m11 = MFMA32(av[1], bk[1], m11, 0, 0, 0);
    }

    float (*part)[64][64] = (float (*)[64][64])pool;  // [2][64][64]
    if (w < 2) {
#pragma unroll
      for (int q = 0; q < 16; ++q) {
        const int cr = (q & 3) + 8 * (q >> 2) + 4 * hi;
        part[w][cr][ln] = m00[q];
        part[w][cr][32 + ln] = m01[q];
        part[w][32 + cr][ln] = m10[q];
        part[w][32 + cr][32 + ln] = m11[q];
      }
    }
    __syncthreads();
    if (w >= 2) {
      const int pw = w - 2;
#pragma unroll
      for (int q = 0; q < 16; ++q) {
        const int cr = (q & 3) + 8 * (q >> 2) + 4 * hi;
        part[pw][cr][ln] += m00[q];
        part[pw][cr][32 + ln] += m01[q];
        part[pw][32 + cr][ln] += m10[q];
        part[pw][32 + cr][32 + ln] += m11[q];
      }
    }
    __syncthreads();
#pragma unroll
    for (int i = 0; i < 16; ++i) {
      const int e = tid + i * 256;
      const int c = e >> 6, cp = e & 63;
      Mws[(size_t)gb * 4096 + c * 64 + cp] =
          (part[0][c][cp] + part[1][c][cp]) * 0.125f;
    }
  }
}

// ============ main kernel: attn (blocks 0..511) + st2 (512..575) ===============
// attn: block = 128 t = 2 t-halves(64 t/wave!) x 2 s-chunks(512 s). Each wave
// computes TWO 32-t MFMA columns from ONE set of K/V fragment reads -> per-work
// LDS traffic halves vs the 32-t/wave structure (the R13-identified binder).
DEVI void stage_pair(ushortT (*lds)[2][16][512], int buf, const ushortT* kbh,
                     const ushortT* vbh, int step, int fpbase, int lane) {
#pragma unroll
  for (int c = 0; c < 2; ++c) {
    const int g = c * 8 + step;
#pragma unroll
    for (int j = 0; j < 4; ++j) {
      const int fp = fpbase + j;
      const ushortT* src =
          (fp < 8 ? kbh + (size_t)g * 4096 + (size_t)fp * 512
                  : vbh + (size_t)g * 4096 + (size_t)(fp - 8) * 512) +
          lane * 8;
      __builtin_amdgcn_global_load_lds(
          (const __attribute__((address_space(1))) void*)src,
          (__attribute__((address_space(3))) void*)&lds[c][buf][fp][0], 16, 0, 0);
    }
  }
}

DEVI void st2_body(const float* __restrict__ st, const float* __restrict__ Mws,
                   float* __restrict__ out1, int sb, int tid, char* pool) {
  const int bh = sb >> 2, tt = sb & 3;
  const int b = bh >> 3, h = bh & 7;
  const float* qbase = st + ((size_t)(b * 1536 + h * 64)) * 1024;
  float* o1 = out1 + ((size_t)(b * 512 + h * 64)) * 1024;
  char* msb = pool;  // 16 KB: Ms[64][64] XOR-swizzled rows

#pragma unroll
  for (int i = 0; i < 16; ++i) {
    const int e = tid + i * 256;
    const int c = e >> 6, cp = e & 63;
    const float* mp = Mws + (size_t)bh * 8 * 4096 + c * 64 + cp;
    float s = 0.f;
#pragma unroll
    for (int ch = 0; ch < 8; ++ch) s += mp[(size_t)ch * 4096];
    *(float*)(msb + c * 256 + ((cp * 4) ^ ((c & 7) << 5))) = s;
  }
  __syncthreads();

  const int w = tid >> 6, lane = tid & 63, hi = lane >> 5, ln = lane & 31;

  short8 aM0[4], aM1[4];
#pragma unroll
  for (int k = 0; k < 4; ++k) {
#pragma unroll
    for (int ci = 0; ci < 2; ++ci) {
      const int row = ci * 32 + ln;
      const int bo = k * 64 + hi * 32;
      const char* rp = msb + row * 256;
      const int swz = (row & 7) << 5;
      f32x4 lo = *(const f32x4*)(rp + (bo ^ swz));
      f32x4 hp = *(const f32x4*)(rp + ((bo + 16) ^ swz));
      U8 u;
      u.u[0] = cvtpk(lo[0], lo[1]); u.u[1] = cvtpk(lo[2], lo[3]);
      u.u[2] = cvtpk(hp[0], hp[1]); u.u[3] = cvtpk(hp[2], hp[3]);
      if (ci) aM1[k] = u.s8; else aM0[k] = u.s8;
    }
  }

#pragma unroll
  for (int nt = 0; nt < 2; ++nt) {
    const int t = tt * 256 + w * 64 + nt * 32 + ln;
    short8 bq[4];
#pragma unroll
    for (int k = 0; k < 4; ++k) {
      const float* qp = qbase + (size_t)(k * 16 + hi * 8) * 1024 + t;
      float q8[8];
#pragma unroll
      for (int j = 0; j < 8; ++j) q8[j] = qp[(size_t)j * 1024];
      U8 u;
#pragma unroll
      for (int i = 0; i < 4; ++i) u.u[i] = cvtpk(q8[2 * i], q8[2 * i + 1]);
      bq[k] = u.s8;
    }
    f32x16 a0 = {}, a1 = {};
#pragma unroll
    for (int k = 0; k < 4; ++k) {
      a0 = MFMA32(aM0[k], bq[k], a0, 0, 0, 0);
      a1 = MFMA32(aM1[k], bq[k], a1, 0, 0, 0);
    }
#pragma unroll
    for (int q = 0; q < 16; ++q) {
      const int cr = (q & 3) + 8 * (q >> 2) + 4 * hi;
      o1[(size_t)cr * 1024 + t] = a0[q];
      o1[(size_t)(cr + 32) * 1024 + t] = a1[q];
    }
  }
}

template <bool WITH_ST2>
__global__ __launch_bounds__(256, 2) void main_kernel(
    const float* __restrict__ img, const ushortT* __restrict__ kfp,
    const ushortT* __restrict__ vfp, const float* __restrict__ st,
    const float* __restrict__ Mws, float* __restrict__ out0,
    float* __restrict__ out1) {
  __shared__ __align__(16) char pool[65536];  // [2 chunk][2 buf][16 frag][512]
  const int tid = threadIdx.x;
  const int bid = blockIdx.x;

  if (WITH_ST2 && bid >= 512) {
    st2_body(st, Mws, out1, bid - 512, tid, pool);
    return;
  }

  const int w = tid >> 6, lane = tid & 63, hi = lane >> 5, ln = lane & 31;
  const int tg = w & 1, sch = w >> 1;  // t-half, s-chunk
  const int bh = bid >> 5, tb = bid & 31;
  const int b = bh >> 3, h = bh & 7;
  const float* qbase = img + ((size_t)(b * 1536 + h * 64)) * 4096;
  float* obase = out0 + ((size_t)(b * 512 + h * 64)) * 4096;

  const int fpbase = w * 4;
  const int tcolA = tb * 128 + tg * 64 + ln;  // t-half A; B = +32

  ushortT (*lds)[2][16][512] = (ushortT (*)[2][16][512])pool;
  const ushortT* kbh = kfp + (size_t)bh * 16 * 4096;
  const ushortT* vbh = vfp + (size_t)bh * 16 * 4096;

  stage_pair(lds, 0, kbh, vbh, 0, fpbase, lane);

  // Q fragments for both t-halves, pre-scaled by C_L2E
  short8 qfA[4], qfB[4];
#pragma unroll
  for (int k = 0; k < 4; ++k) {
    const float* qp = qbase + (size_t)(k * 16 + hi * 8) * 4096 + tcolA;
    float qa[8], qb[8];
#pragma unroll
    for (int j = 0; j < 8; ++j) {
      qa[j] = qp[(size_t)j * 4096] * C_L2E;
      qb[j] = qp[(size_t)j * 4096 + 32] * C_L2E;
    }
    U8 ua, ub;
#pragma unroll
    for (int i = 0; i < 4; ++i) {
      ua.u[i] = cvtpk(qa[2 * i], qa[2 * i + 1]);
      ub.u[i] = cvtpk(qb[2 * i], qb[2 * i + 1]);
    }
    qfA[k] = ua.s8;
    qfB[k] = ub.s8;
  }

  f32x16 oA0 = {}, oA1 = {}, oB0 = {}, oB1 = {};
  float laA0 = 0.f, laA1 = 0.f, laA2 = 0.f, laA3 = 0.f;
  float laB0 = 0.f, laB1 = 0.f, laB2 = 0.f, laB3 = 0.f;

  __syncthreads();  // pair 0 staged

  for (int i = 0; i < 8; ++i) {
    const ushortT(*L)[512] = lds[sch][i & 1];

    // QK^T: one K-frag read feeds BOTH t-halves (2x work per LDS byte)
    f32x16 sA0 = {}, sA1 = {}, sB0 = {}, sB1 = {};
    {
      short8 kf[8];
#pragma unroll
      for (int f = 0; f < 8; ++f) kf[f] = *(const short8*)&L[f][lane * 8];
      __builtin_amdgcn_s_setprio(1);
      sA0 = MFMA32(kf[0], qfA[0], sA0, 0, 0, 0);
      sB0 = MFMA32(kf[0], qfB[0], sB0, 0, 0, 0);
      sA1 = MFMA32(kf[4], qfA[0], sA1, 0, 0, 0);
      sB1 = MFMA32(kf[4], qfB[0], sB1, 0, 0, 0);
      sA0 = MFMA32(kf[1], qfA[1], sA0, 0, 0, 0);
      sB0 = MFMA32(kf[1], qfB[1], sB0, 0, 0, 0);
      sA1 = MFMA32(kf[5], qfA[1], sA1, 0, 0, 0);
      sB1 = MFMA32(kf[5], qfB[1], sB1, 0, 0, 0);
      sA0 = MFMA32(kf[2], qfA[2], sA0, 0, 0, 0);
      sB0 = MFMA32(kf[2], qfB[2], sB0, 0, 0, 0);
      sA1 = MFMA32(kf[6], qfA[2], sA1, 0, 0, 0);
      sB1 = MFMA32(kf[6], qfB[2], sB1, 0, 0, 0);
      sA0 = MFMA32(kf[3], qfA[3], sA0, 0, 0, 0);
      sB0 = MFMA32(kf[3], qfB[3], sB0, 0, 0, 0);
      sA1 = MFMA32(kf[7], qfA[3], sA1, 0, 0, 0);
      sB1 = MFMA32(kf[7], qfB[3], sB1, 0, 0, 0);
      __builtin_amdgcn_s_setprio(0);
    }

    // stage next tile-pair into the other buffer
    if (i + 1 < 8) stage_pair(lds, (i + 1) & 1, kbh, vbh, i + 1, fpbase, lane);

    // p = exp2(S'); l accumulated (no max, no rescale)
#pragma unroll
    for (int q = 0; q < 16; q += 4) {
      float p0 = exp2a(sA0[q]), p1 = exp2a(sA0[q + 1]);
      float p2 = exp2a(sA0[q + 2]), p3 = exp2a(sA0[q + 3]);
      sA0[q] = p0; sA0[q + 1] = p1; sA0[q + 2] = p2; sA0[q + 3] = p3;
      laA0 += p0; laA1 += p1; laA2 += p2; laA3 += p3;
    }
#pragma unroll
    for (int q = 0; q < 16; q += 4) {
      float p0 = exp2a(sA1[q]), p1 = exp2a(sA1[q + 1]);
      float p2 = exp2a(sA1[q + 2]), p3 = exp2a(sA1[q + 3]);
      sA1[q] = p0; sA1[q + 1] = p1; sA1[q + 2] = p2; sA1[q + 3] = p3;
      laA0 += p0; laA1 += p1; laA2 += p2; laA3 += p3;
    }
#pragma unroll
    for (int q = 0; q < 16; q += 4) {
      float p0 = exp2a(sB0[q]), p1 = exp2a(sB0[q + 1]);
      float p2 = exp2a(sB0[q + 2]), p3 = exp2a(sB0[q + 3]);
      sB0[q] = p0; sB0[q + 1] = p1; sB0[q + 2] = p2; sB0[q + 3] = p3;
      laB0 += p0; laB1 += p1; laB2 += p2; laB3 += p3;
    }
#pragma unroll
    for (int q = 0; q < 16; q += 4) {
      float p0 = exp2a(sB1[q]), p1 = exp2a(sB1[q + 1]);
      float p2 = exp2a(sB1[q + 2]), p3 = exp2a(sB1[q + 3]);
      sB1[q] = p0; sB1[q + 1] = p1; sB1[q + 2] = p2; sB1[q + 3] = p3;
      laB0 += p0; laB1 += p1; laB2 += p2; laB3 += p3;
    }

    // PV: one V-frag read feeds both t-halves; B-frags = lane's own cvtpk(P)
#pragma unroll
    for (int ss = 0; ss < 2; ++ss) {
      const f32x16& a = ss ? sA1 : sA0;
      const f32x16& bb = ss ? sB1 : sB0;
      U8 A0, A1, B0, B1;
      A0.u[0] = cvtpk(a[0], a[1]);    A0.u[1] = cvtpk(a[2], a[3]);
      A0.u[2] = cvtpk(a[4], a[5]);    A0.u[3] = cvtpk(a[6], a[7]);
      A1.u[0] = cvtpk(a[8], a[9]);    A1.u[1] = cvtpk(a[10], a[11]);
      A1.u[2] = cvtpk(a[12], a[13]);  A1.u[3] = cvtpk(a[14], a[15]);
      B0.u[0] = cvtpk(bb[0], bb[1]);   B0.u[1] = cvtpk(bb[2], bb[3]);
      B0.u[2] = cvtpk(bb[4], bb[5]);   B0.u[3] = cvtpk(bb[6], bb[7]);
      B1.u[0] = cvtpk(bb[8], bb[9]);   B1.u[1] = cvtpk(bb[10], bb[11]);
      B1.u[2] = cvtpk(bb[12], bb[13]); B1.u[3] = cvtpk(bb[14], bb[15]);
      short8 v0 = *(const short8*)&L[8 + ss * 4 + 0][lane * 8];
      short8 v1 = *(const short8*)&L[8 + ss * 4 + 1][lane * 8];
      short8 v2 = *(const short8*)&L[8 + ss * 4 + 2][lane * 8];
      short8 v3 = *(const short8*)&L[8 + ss * 4 + 3][lane * 8];
      __builtin_amdgcn_s_setprio(1);
      oA0 = MFMA32(v0, A0.s8, oA0, 0, 0, 0);
      oA1 = MFMA32(v1, A0.s8, oA1, 0, 0, 0);
      oB0 = MFMA32(v0, B0.s8, oB0, 0, 0, 0);
      oB1 = MFMA32(v1, B0.s8, oB1, 0, 0, 0);
      oA0 = MFMA32(v2, A1.s8, oA0, 0, 0, 0);
      oA1 = MFMA32(v3, A1.s8, oA1, 0, 0, 0);
      oB0 = MFMA32(v2, B1.s8, oB0, 0, 0, 0);
      oB1 = MFMA32(v3, B1.s8, oB1, 0, 0, 0);
      __builtin_amdgcn_s_setprio(0);
    }
    if (i + 1 < 8) __syncthreads();
  }

  float lA = (laA0 + laA1) + (laA2 + laA3);
  lA += __shfl_xor(lA, 32);
  float lB = (laB0 + laB1) + (laB2 + laB3);
  lB += __shfl_xor(lB, 32);

  // merge the two s-chunks (sch 0 <- 1) by addition; normalize + store
  __syncthreads();
  float (*mrg)[64][66] = (float (*)[64][66])pool;
  if (sch == 1) {
#pragma unroll
    for (int q = 0; q < 16; ++q) {
      mrg[tg][lane][q] = oA0[q];
      mrg[tg][lane][16 + q] = oA1[q];
      mrg[tg][lane][32 + q] = oB0[q];
      mrg[tg][lane][48 + q] = oB1[q];
    }
    mrg[tg][lane][64] = lA;
    mrg[tg][lane][65] = lB;
  }
  __syncthreads();
  if (sch == 0) {
    const float liA = 1.0f / (lA + mrg[tg][lane][64]);
    const float liB = 1.0f / (lB + mrg[tg][lane][65]);
#pragma unroll
    for (int q = 0; q < 16; ++q) {
      const int c = (q & 3) + 8 * (q >> 2) + 4 * hi;
      obase[(size_t)c * 4096 + tcolA] = (oA0[q] + mrg[tg][lane][q]) * liA;
      obase[(size_t)(c + 32) * 4096 + tcolA] = (oA1[q] + mrg[tg][lane][16 + q]) * liA;
      obase[(size_t)c * 4096 + tcolA + 32] = (oB0[q] + mrg[tg][lane][32 + q]) * liB;
      obase[(size_t)(c + 32) * 4096 + tcolA + 32] =
          (oB1[q] + mrg[tg][lane][48 + q]) * liB;
    }
  }
}

// standalone st2 for the small-ws fallback (runs after main; out1 reuse safe)
__global__ __launch_bounds__(256) void st2_kernel(
    const float* __restrict__ st, const float* __restrict__ Mws,
    float* __restrict__ out1) {
  __shared__ __align__(16) char pool[16384];
  st2_body(st, Mws, out1, blockIdx.x, threadIdx.x, pool);
}

extern "C" void kernel_launch(void* const* d_in, const int* in_sizes, int n_in,
                              void* d_out, int out_size, void* d_ws, size_t ws_size,
                              hipStream_t stream) {
  const float* img = (const float*)d_in[0];
  const float* st = (const float*)d_in[1];
  float* out0 = (float*)d_out;
  float* out1 = out0 + (size_t)2 * 512 * 4096;
  char* ws = (char*)d_ws;
  const size_t MB = 1u << 20;

  ushortT* kfp;
  ushortT* vfp;
  float* Ms;
  bool fits = ws_size >= 6 * MB;
  if (fits) {
    kfp = (ushortT*)ws; vfp = (ushortT*)(ws + 2 * MB); Ms = (float*)(ws + 4 * MB);
  } else {
    // stash packed K/V in out1's region (4 MB); st2 runs after main and
    // overwrites it last (kernel order on the stream guarantees safety)
    kfp = (ushortT*)out1; vfp = (ushortT*)((char*)out1 + 2 * MB);
    Ms = (float*)ws;  // needs 2 MB
  }

  hipLaunchKernelGGL(aux_kernel, dim3(384), dim3(256), 0, stream, img, st, kfp,
                     vfp, Ms);
  if (fits) {
    hipLaunchKernelGGL((main_kernel<true>), dim3(576), dim3(256), 0, stream, img,
                       kfp, vfp, st, Ms, out0, out1);
  } else {
    hipLaunchKernelGGL((main_kernel<false>), dim3(512), dim3(256), 0, stream, img,
                       kfp, vfp, st, Ms, out0, out1);
    hipLaunchKernelGGL(st2_kernel, dim3(64), dim3(256), 0, stream, st, Ms, out1);
  }
}